// Round 1
// baseline (656.984 us; speedup 1.0000x reference)
//
#include <hip/hip_runtime.h>
#include <math.h>

#define B_     32
#define N_     20
#define D_     64
#define NODE_F 16
#define EDGE_F 8
#define E_PER  40
#define PROP   5
#define NC2    190
#define ITERS  20
#define INV_TEMP 10.0f
#define TN (2*B_*N_)    // 1280 nodes
#define TE (2*B_*E_PER) // 2560 edges
#define NG (2*B_)       // 64 graphs

struct PairTab { int s[NC2]; int d[NC2]; };
constexpr PairTab make_pairs() {
    PairTab t{};
    int idx = 0;
    for (int i = 0; i < N_; ++i)
        for (int j = i + 1; j < N_; ++j) { t.s[idx] = i; t.d[idx] = j; ++idx; }
    return t;
}
__device__ constexpr PairTab PAIRS = make_pairs();

// lane-broadcast: read element k of a lane-distributed vector (uniform k)
__device__ __forceinline__ float rlane(float x, int k) {
#if __has_builtin(__builtin_amdgcn_readlane)
    return __int_as_float(__builtin_amdgcn_readlane(__float_as_int(x), k));
#else
    return __shfl(x, k, 64);
#endif
}

// ---------------------------------------------------------------- encode
__global__ __launch_bounds__(256) void k_encode(
    const float* __restrict__ nf, const float* __restrict__ ef,
    const float* __restrict__ Wn, const float* __restrict__ bn,
    const float* __restrict__ We, const float* __restrict__ be,
    float* __restrict__ h, float* __restrict__ eemb, float* __restrict__ agg)
{
    int gid = blockIdx.x * 256 + threadIdx.x;
    int f = gid & 63, r = gid >> 6;
    if (r < TN) {
        float acc = bn[f];
#pragma unroll
        for (int k = 0; k < NODE_F; ++k) acc += nf[r * NODE_F + k] * Wn[k * D_ + f];
        h[r * D_ + f] = acc;
        agg[r * D_ + f] = 0.f;
    } else if (r < TN + TE) {
        int r2 = r - TN;
        float acc = be[f];
#pragma unroll
        for (int k = 0; k < EDGE_F; ++k) acc += ef[r2 * EDGE_F + k] * We[k * D_ + f];
        eemb[r2 * D_ + f] = acc;
    }
}

// ---------------------------------------------------------------- message + aggregate
#define EPW 4
__global__ __launch_bounds__(256) void k_msg(
    const float* __restrict__ h, const float* __restrict__ eemb,
    const int* __restrict__ fidx, const int* __restrict__ tidx,
    const float* __restrict__ Wm1, const float* __restrict__ bm1,
    const float* __restrict__ Wm2, const float* __restrict__ bm2,
    float* __restrict__ agg)
{
    int wid = (blockIdx.x * 256 + threadIdx.x) >> 6;
    int f = threadIdx.x & 63;
    int ebase = wid * EPW;
    float xf[EPW], xt[EPW], xe[EPW];
    int to[EPW];
#pragma unroll
    for (int s = 0; s < EPW; ++s) {
        int e = ebase + s;
        int fr = fidx[e]; to[s] = tidx[e];
        xf[s] = h[fr * D_ + f];
        xt[s] = h[to[s] * D_ + f];
        xe[s] = eemb[e * D_ + f];
    }
    float b1 = bm1[f];
    float acc[EPW];
#pragma unroll
    for (int s = 0; s < EPW; ++s) acc[s] = b1;
#pragma unroll 4
    for (int k = 0; k < D_; ++k) {
        float w0 = Wm1[k * D_ + f];
        float w1 = Wm1[(D_ + k) * D_ + f];
        float w2 = Wm1[(2 * D_ + k) * D_ + f];
#pragma unroll
        for (int s = 0; s < EPW; ++s)
            acc[s] += rlane(xf[s], k) * w0 + rlane(xt[s], k) * w1 + rlane(xe[s], k) * w2;
    }
    float b2 = bm2[f];
    float out[EPW];
#pragma unroll
    for (int s = 0; s < EPW; ++s) { acc[s] = fmaxf(acc[s], 0.f); out[s] = b2; }
#pragma unroll 4
    for (int k = 0; k < D_; ++k) {
        float w = Wm2[k * D_ + f];
#pragma unroll
        for (int s = 0; s < EPW; ++s) out[s] += rlane(acc[s], k) * w;
    }
#pragma unroll
    for (int s = 0; s < EPW; ++s) atomicAdd(&agg[to[s] * D_ + f], out[s]);
}

// ---------------------------------------------------------------- node update (in-place, re-zeroes agg)
#define NPW 2
__global__ __launch_bounds__(256) void k_update(
    float* __restrict__ h, float* __restrict__ agg,
    const float* __restrict__ Wu1, const float* __restrict__ bu1,
    const float* __restrict__ Wu2, const float* __restrict__ bu2)
{
    int wid = (blockIdx.x * 256 + threadIdx.x) >> 6;
    int f = threadIdx.x & 63;
    int nbase = wid * NPW;
    float xh[NPW], xa[NPW];
#pragma unroll
    for (int s = 0; s < NPW; ++s) {
        xh[s] = h[(nbase + s) * D_ + f];
        xa[s] = agg[(nbase + s) * D_ + f];
    }
    float b1 = bu1[f];
    float acc[NPW];
#pragma unroll
    for (int s = 0; s < NPW; ++s) acc[s] = b1;
#pragma unroll 4
    for (int k = 0; k < D_; ++k) {
        float w0 = Wu1[k * D_ + f];
        float w1 = Wu1[(D_ + k) * D_ + f];
#pragma unroll
        for (int s = 0; s < NPW; ++s)
            acc[s] += rlane(xh[s], k) * w0 + rlane(xa[s], k) * w1;
    }
    float b2 = bu2[f];
    float out[NPW];
#pragma unroll
    for (int s = 0; s < NPW; ++s) { acc[s] = fmaxf(acc[s], 0.f); out[s] = b2; }
#pragma unroll 4
    for (int k = 0; k < D_; ++k) {
        float w = Wu2[k * D_ + f];
#pragma unroll
        for (int s = 0; s < NPW; ++s) out[s] += rlane(acc[s], k) * w;
    }
#pragma unroll
    for (int s = 0; s < NPW; ++s) {
        h[(nbase + s) * D_ + f] = out[s];
        agg[(nbase + s) * D_ + f] = 0.f;   // ready for next prop step
    }
}

// ---------------------------------------------------------------- similarity: T MLP, cost, 20x20 sinkhorn, esi -> la0 / la0T
__global__ __launch_bounds__(256) void k_sim(
    const float* __restrict__ h,
    const float* __restrict__ Ws1, const float* __restrict__ bs1,
    const float* __restrict__ Ws2, const float* __restrict__ bs2,
    float* __restrict__ la0, float* __restrict__ la0T)
{
    __shared__ float sH[2][N_][D_];
    __shared__ float sA[2][N_][N_];
    __shared__ float sT[2][N_][N_];
    __shared__ float sLa[N_][N_];
    __shared__ float sU[N_], sV[N_];
    __shared__ float sP[N_][N_];
    int b = blockIdx.x, t = threadIdx.x;

    for (int idx = t; idx < 2 * N_ * D_; idx += 256) {
        int s = idx / (N_ * D_), rem = idx % (N_ * D_), i = rem / D_, f = rem % D_;
        sH[s][i][f] = h[((2 * b + s) * N_ + i) * D_ + f];
    }
    __syncthreads();
    for (int idx = t; idx < 2 * N_ * N_; idx += 256) {
        int s = idx / (N_ * N_), rem = idx % (N_ * N_), i = rem / N_, k = rem % N_;
        float a = bs1[k];
        for (int ff = 0; ff < D_; ++ff) a += sH[s][i][ff] * Ws1[ff * N_ + k];
        sA[s][i][k] = fmaxf(a, 0.f);
    }
    __syncthreads();
    for (int idx = t; idx < 2 * N_ * N_; idx += 256) {
        int s = idx / (N_ * N_), rem = idx % (N_ * N_), i = rem / N_, k = rem % N_;
        float a = bs2[k];
        for (int j = 0; j < N_; ++j) a += sA[s][i][j] * Ws2[j * N_ + k];
        sT[s][i][k] = a;
    }
    __syncthreads();
    for (int idx = t; idx < N_ * N_; idx += 256) {
        int i = idx / N_, j = idx % N_;
        float c = 0.f;
        for (int k = 0; k < N_; ++k) c += fabsf(sT[0][i][k] - sT[1][j][k]);
        sLa[i][j] = -c * INV_TEMP;
    }
    if (t < N_) sV[t] = 0.f;
    __syncthreads();
    // sinkhorn in u/v potential form (matrix never rewritten)
    for (int it = 0; it < ITERS; ++it) {
        if (t < N_) {
            float m = -1e30f;
            for (int q = 0; q < N_; ++q) m = fmaxf(m, sLa[t][q] - sV[q]);
            float ss = 0.f;
            for (int q = 0; q < N_; ++q) ss += __expf(sLa[t][q] - sV[q] - m);
            sU[t] = m + __logf(ss);
        }
        __syncthreads();
        if (t < N_) {
            float m = -1e30f;
            for (int p = 0; p < N_; ++p) m = fmaxf(m, sLa[p][t] - sU[p]);
            float ss = 0.f;
            for (int p = 0; p < N_; ++p) ss += __expf(sLa[p][t] - sU[p] - m);
            sV[t] = m + __logf(ss);
        }
        __syncthreads();
    }
    for (int idx = t; idx < N_ * N_; idx += 256) {
        int i = idx / N_, j = idx % N_;
        sP[i][j] = __expf(sLa[i][j] - sU[i] - sV[j]);
    }
    __syncthreads();
    size_t base = (size_t)b * NC2 * NC2;
    for (int idx = t; idx < NC2 * NC2; idx += 256) {
        int p = idx / NC2, q = idx - p * NC2;
        int sp = PAIRS.s[p], dp = PAIRS.d[p], sq = PAIRS.s[q], dq = PAIRS.d[q];
        float st = sP[sp][sq] * sP[dp][dq];
        float cr = sP[sp][dq] * sP[dp][sq];
        float lv = __logf(fmaxf(st, cr) + 1e-6f) * INV_TEMP;
        la0[base + idx] = lv;
        la0T[base + (size_t)q * NC2 + p] = lv;
    }
}

// ---------------------------------------------------------------- NC2 pair-edge embeddings (fwd+bwd fused)
#define PPW 4
__global__ __launch_bounds__(256) void k_edge(
    const float* __restrict__ h,
    const float* __restrict__ qadj, const float* __restrict__ cadj,
    const float* __restrict__ Wl1, const float* __restrict__ bl1,
    const float* __restrict__ Wl2, const float* __restrict__ bl2,
    float* __restrict__ emb)
{
    int wid = (blockIdx.x * 256 + threadIdx.x) >> 6;
    int f = threadIdx.x & 63;
    int base = wid * PPW;
    float sv[PPW], dv[PPW], av[PPW];
#pragma unroll
    for (int s = 0; s < PPW; ++s) {
        int slot = base + s;
        int g = slot / NC2, p = slot - g * NC2;
        int sp = PAIRS.s[p], dp = PAIRS.d[p];
        sv[s] = h[(g * N_ + sp) * D_ + f];
        dv[s] = h[(g * N_ + dp) * D_ + f];
        const float* adj = (g & 1) ? cadj : qadj;
        av[s] = adj[(g >> 1) * N_ * N_ + sp * N_ + dp];
    }
    float b1 = bl1[f];
    float w128 = Wl1[128 * D_ + f];
    float aF[PPW], aB[PPW];
#pragma unroll
    for (int s = 0; s < PPW; ++s) { float t0 = b1 + av[s] * w128; aF[s] = t0; aB[s] = t0; }
#pragma unroll 2
    for (int k = 0; k < D_; ++k) {
        float w0 = Wl1[k * D_ + f];
        float w1 = Wl1[(D_ + k) * D_ + f];
#pragma unroll
        for (int s = 0; s < PPW; ++s) {
            float a = rlane(sv[s], k), c = rlane(dv[s], k);
            aF[s] += a * w0 + c * w1;
            aB[s] += c * w0 + a * w1;
        }
    }
    float b2 = 2.f * bl2[f];
    float hs[PPW], out[PPW];
#pragma unroll
    for (int s = 0; s < PPW; ++s) {
        hs[s] = fmaxf(aF[s], 0.f) + fmaxf(aB[s], 0.f);
        out[s] = b2;
    }
#pragma unroll 4
    for (int k = 0; k < D_; ++k) {
        float w = Wl2[k * D_ + f];
#pragma unroll
        for (int s = 0; s < PPW; ++s) out[s] += rlane(hs[s], k) * w;
    }
#pragma unroll
    for (int s = 0; s < PPW; ++s) emb[(size_t)(base + s) * D_ + f] = out[s];
}

// ---------------------------------------------------------------- 190x190 sinkhorn (u/v form) -> eplan in-place; zeroes d_out
__global__ __launch_bounds__(1024) void k_sink190(
    float* __restrict__ la0, const float* __restrict__ la0T, float* __restrict__ dout)
{
    __shared__ float sU[NC2], sV[NC2];
    int b = blockIdx.x, t = threadIdx.x;
    int w = t >> 6, l = t & 63;
    float* la = la0 + (size_t)b * NC2 * NC2;
    const float* laT = la0T + (size_t)b * NC2 * NC2;
    if (t < NC2) sV[t] = 0.f;
    if (t == 0) dout[b] = 0.f;
    __syncthreads();
    for (int it = 0; it < ITERS; ++it) {
        for (int p = w; p < NC2; p += 16) {
            const float* row = la + (size_t)p * NC2;
            float v0 = row[l] - sV[l];
            float v1 = row[l + 64] - sV[l + 64];
            float v2 = (l + 128 < NC2) ? row[l + 128] - sV[l + 128] : -1e30f;
            float m = fmaxf(fmaxf(v0, v1), v2);
#pragma unroll
            for (int off = 32; off; off >>= 1) m = fmaxf(m, __shfl_xor(m, off));
            float ss = __expf(v0 - m) + __expf(v1 - m) + __expf(v2 - m);
#pragma unroll
            for (int off = 32; off; off >>= 1) ss += __shfl_xor(ss, off);
            if (l == 0) sU[p] = m + __logf(ss);
        }
        __syncthreads();
        for (int q = w; q < NC2; q += 16) {
            const float* col = laT + (size_t)q * NC2;
            float v0 = col[l] - sU[l];
            float v1 = col[l + 64] - sU[l + 64];
            float v2 = (l + 128 < NC2) ? col[l + 128] - sU[l + 128] : -1e30f;
            float m = fmaxf(fmaxf(v0, v1), v2);
#pragma unroll
            for (int off = 32; off; off >>= 1) m = fmaxf(m, __shfl_xor(m, off));
            float ss = __expf(v0 - m) + __expf(v1 - m) + __expf(v2 - m);
#pragma unroll
            for (int off = 32; off; off >>= 1) ss += __shfl_xor(ss, off);
            if (l == 0) sV[q] = m + __logf(ss);
        }
        __syncthreads();
    }
    for (int idx = t; idx < NC2 * NC2; idx += 1024) {
        int p = idx / NC2, q = idx - p * NC2;
        la[idx] = __expf(la[idx] - sU[p] - sV[q]);   // eplan, in place
    }
}

// ---------------------------------------------------------------- final weighted L1 contraction
__global__ __launch_bounds__(256) void k_dist(
    const float* __restrict__ emb, const float* __restrict__ eplan, float* __restrict__ dout)
{
    int b = blockIdx.x, c = blockIdx.y;
    int w = threadIdx.x >> 6, l = threadIdx.x & 63;
    const float* qe = emb + (size_t)(2 * b) * NC2 * D_;
    const float* ce = emb + (size_t)(2 * b + 1) * NC2 * D_;
    const float* W = eplan + (size_t)b * NC2 * NC2;
    float acc = 0.f;
    int pbase = c * 16 + w * 4;
    for (int i = 0; i < 4; ++i) {
        int p = pbase + i;
        if (p >= NC2) break;
        float qv = qe[(size_t)p * D_ + l];
        const float* wrow = W + (size_t)p * NC2;
        for (int q = 0; q < NC2; ++q)
            acc += wrow[q] * fabsf(qv - ce[(size_t)q * D_ + l]);
    }
#pragma unroll
    for (int off = 32; off; off >>= 1) acc += __shfl_xor(acc, off);
    if (l == 0) atomicAdd(&dout[b], acc);
}

// ---------------------------------------------------------------- launch
extern "C" void kernel_launch(void* const* d_in, const int* in_sizes, int n_in,
                              void* d_out, int out_size, void* d_ws, size_t ws_size,
                              hipStream_t stream)
{
    const float* nf   = (const float*)d_in[0];
    const float* ef   = (const float*)d_in[1];
    const float* qadj = (const float*)d_in[2];
    const float* cadj = (const float*)d_in[3];
    const int*   fidx = (const int*)d_in[4];
    const int*   tidx = (const int*)d_in[5];
    const float* Wn  = (const float*)d_in[6];  const float* bn  = (const float*)d_in[7];
    const float* We  = (const float*)d_in[8];  const float* be  = (const float*)d_in[9];
    const float* Wm1 = (const float*)d_in[10]; const float* bm1 = (const float*)d_in[11];
    const float* Wm2 = (const float*)d_in[12]; const float* bm2 = (const float*)d_in[13];
    const float* Wu1 = (const float*)d_in[14]; const float* bu1 = (const float*)d_in[15];
    const float* Wu2 = (const float*)d_in[16]; const float* bu2 = (const float*)d_in[17];
    const float* Ws1 = (const float*)d_in[18]; const float* bs1 = (const float*)d_in[19];
    const float* Ws2 = (const float*)d_in[20]; const float* bs2 = (const float*)d_in[21];
    const float* Wl1 = (const float*)d_in[22]; const float* bl1 = (const float*)d_in[23];
    const float* Wl2 = (const float*)d_in[24]; const float* bl2 = (const float*)d_in[25];

    float* ws   = (float*)d_ws;
    float* h    = ws;                          // TN*D
    float* agg  = h    + (size_t)TN * D_;      // TN*D
    float* eemb = agg  + (size_t)TN * D_;      // TE*D
    float* emb  = eemb + (size_t)TE * D_;      // NG*NC2*D
    float* la0  = emb  + (size_t)NG * NC2 * D_;    // B*NC2*NC2
    float* la0T = la0  + (size_t)B_ * NC2 * NC2;   // B*NC2*NC2
    float* dout = (float*)d_out;

    k_encode<<<(TN + TE) * D_ / 256, 256, 0, stream>>>(nf, ef, Wn, bn, We, be, h, eemb, agg);
    for (int s = 0; s < PROP; ++s) {
        k_msg<<<TE / EPW / 4, 256, 0, stream>>>(h, eemb, fidx, tidx, Wm1, bm1, Wm2, bm2, agg);
        k_update<<<TN / NPW / 4, 256, 0, stream>>>(h, agg, Wu1, bu1, Wu2, bu2);
    }
    k_sim<<<B_, 256, 0, stream>>>(h, Ws1, bs1, Ws2, bs2, la0, la0T);
    k_edge<<<NG * NC2 / PPW / 4, 256, 0, stream>>>(h, qadj, cadj, Wl1, bl1, Wl2, bl2, emb);
    k_sink190<<<B_, 1024, 0, stream>>>(la0, la0T, dout);
    k_dist<<<dim3(B_, 12), 256, 0, stream>>>(emb, la0, dout);
}

// Round 2
// 465.942 us; speedup vs baseline: 1.4100x; 1.4100x over previous
//
#include <hip/hip_runtime.h>
#include <math.h>

#define B_     32
#define N_     20
#define D_     64
#define NODE_F 16
#define EDGE_F 8
#define E_PER  40
#define PROP   5
#define NC2    190
#define ITERS  20
#define INV_TEMP 10.0f
#define TN (2*B_*N_)    // 1280 nodes
#define TE (2*B_*E_PER) // 2560 edges
#define NG (2*B_)       // 64 graphs

struct PairTab { int s[NC2]; int d[NC2]; };
constexpr PairTab make_pairs() {
    PairTab t{};
    int idx = 0;
    for (int i = 0; i < N_; ++i)
        for (int j = i + 1; j < N_; ++j) { t.s[idx] = i; t.d[idx] = j; ++idx; }
    return t;
}
__device__ constexpr PairTab PAIRS = make_pairs();

// lane-broadcast: read element k of a lane-distributed vector (uniform k)
__device__ __forceinline__ float rlane(float x, int k) {
#if __has_builtin(__builtin_amdgcn_readlane)
    return __int_as_float(__builtin_amdgcn_readlane(__float_as_int(x), k));
#else
    return __shfl(x, k, 64);
#endif
}

// ---------------------------------------------------------------- encode
__global__ __launch_bounds__(256) void k_encode(
    const float* __restrict__ nf, const float* __restrict__ ef,
    const float* __restrict__ Wn, const float* __restrict__ bn,
    const float* __restrict__ We, const float* __restrict__ be,
    float* __restrict__ h, float* __restrict__ eemb, float* __restrict__ agg)
{
    int gid = blockIdx.x * 256 + threadIdx.x;
    int f = gid & 63, r = gid >> 6;
    if (r < TN) {
        float acc = bn[f];
#pragma unroll
        for (int k = 0; k < NODE_F; ++k) acc += nf[r * NODE_F + k] * Wn[k * D_ + f];
        h[r * D_ + f] = acc;
        agg[r * D_ + f] = 0.f;
    } else if (r < TN + TE) {
        int r2 = r - TN;
        float acc = be[f];
#pragma unroll
        for (int k = 0; k < EDGE_F; ++k) acc += ef[r2 * EDGE_F + k] * We[k * D_ + f];
        eemb[r2 * D_ + f] = acc;
    }
}

// ---------------------------------------------------------------- message + aggregate
#define EPW 4
__global__ __launch_bounds__(256) void k_msg(
    const float* __restrict__ h, const float* __restrict__ eemb,
    const int* __restrict__ fidx, const int* __restrict__ tidx,
    const float* __restrict__ Wm1, const float* __restrict__ bm1,
    const float* __restrict__ Wm2, const float* __restrict__ bm2,
    float* __restrict__ agg)
{
    int wid = (blockIdx.x * 256 + threadIdx.x) >> 6;
    int f = threadIdx.x & 63;
    int ebase = wid * EPW;
    float xf[EPW], xt[EPW], xe[EPW];
    int to[EPW];
#pragma unroll
    for (int s = 0; s < EPW; ++s) {
        int e = ebase + s;
        int fr = fidx[e]; to[s] = tidx[e];
        xf[s] = h[fr * D_ + f];
        xt[s] = h[to[s] * D_ + f];
        xe[s] = eemb[e * D_ + f];
    }
    float b1 = bm1[f];
    float acc[EPW];
#pragma unroll
    for (int s = 0; s < EPW; ++s) acc[s] = b1;
#pragma unroll 4
    for (int k = 0; k < D_; ++k) {
        float w0 = Wm1[k * D_ + f];
        float w1 = Wm1[(D_ + k) * D_ + f];
        float w2 = Wm1[(2 * D_ + k) * D_ + f];
#pragma unroll
        for (int s = 0; s < EPW; ++s)
            acc[s] += rlane(xf[s], k) * w0 + rlane(xt[s], k) * w1 + rlane(xe[s], k) * w2;
    }
    float b2 = bm2[f];
    float out[EPW];
#pragma unroll
    for (int s = 0; s < EPW; ++s) { acc[s] = fmaxf(acc[s], 0.f); out[s] = b2; }
#pragma unroll 4
    for (int k = 0; k < D_; ++k) {
        float w = Wm2[k * D_ + f];
#pragma unroll
        for (int s = 0; s < EPW; ++s) out[s] += rlane(acc[s], k) * w;
    }
#pragma unroll
    for (int s = 0; s < EPW; ++s) atomicAdd(&agg[to[s] * D_ + f], out[s]);
}

// ---------------------------------------------------------------- node update (in-place, re-zeroes agg)
#define NPW 2
__global__ __launch_bounds__(256) void k_update(
    float* __restrict__ h, float* __restrict__ agg,
    const float* __restrict__ Wu1, const float* __restrict__ bu1,
    const float* __restrict__ Wu2, const float* __restrict__ bu2)
{
    int wid = (blockIdx.x * 256 + threadIdx.x) >> 6;
    int f = threadIdx.x & 63;
    int nbase = wid * NPW;
    float xh[NPW], xa[NPW];
#pragma unroll
    for (int s = 0; s < NPW; ++s) {
        xh[s] = h[(nbase + s) * D_ + f];
        xa[s] = agg[(nbase + s) * D_ + f];
    }
    float b1 = bu1[f];
    float acc[NPW];
#pragma unroll
    for (int s = 0; s < NPW; ++s) acc[s] = b1;
#pragma unroll 4
    for (int k = 0; k < D_; ++k) {
        float w0 = Wu1[k * D_ + f];
        float w1 = Wu1[(D_ + k) * D_ + f];
#pragma unroll
        for (int s = 0; s < NPW; ++s)
            acc[s] += rlane(xh[s], k) * w0 + rlane(xa[s], k) * w1;
    }
    float b2 = bu2[f];
    float out[NPW];
#pragma unroll
    for (int s = 0; s < NPW; ++s) { acc[s] = fmaxf(acc[s], 0.f); out[s] = b2; }
#pragma unroll 4
    for (int k = 0; k < D_; ++k) {
        float w = Wu2[k * D_ + f];
#pragma unroll
        for (int s = 0; s < NPW; ++s) out[s] += rlane(acc[s], k) * w;
    }
#pragma unroll
    for (int s = 0; s < NPW; ++s) {
        h[(nbase + s) * D_ + f] = out[s];
        agg[(nbase + s) * D_ + f] = 0.f;   // ready for next prop step
    }
}

// ---------------------------------------------------------------- similarity: T MLP, cost, 20x20 sinkhorn -> P (20x20 per batch)
__global__ __launch_bounds__(256) void k_sim(
    const float* __restrict__ h,
    const float* __restrict__ Ws1, const float* __restrict__ bs1,
    const float* __restrict__ Ws2, const float* __restrict__ bs2,
    float* __restrict__ Pg)
{
    __shared__ float sH[2][N_][D_];
    __shared__ float sA[2][N_][N_];
    __shared__ float sT[2][N_][N_];
    __shared__ float sLa[N_][N_];
    __shared__ float sU[N_], sV[N_];
    int b = blockIdx.x, t = threadIdx.x;

    for (int idx = t; idx < 2 * N_ * D_; idx += 256) {
        int s = idx / (N_ * D_), rem = idx % (N_ * D_), i = rem / D_, f = rem % D_;
        sH[s][i][f] = h[((2 * b + s) * N_ + i) * D_ + f];
    }
    __syncthreads();
    for (int idx = t; idx < 2 * N_ * N_; idx += 256) {
        int s = idx / (N_ * N_), rem = idx % (N_ * N_), i = rem / N_, k = rem % N_;
        float a = bs1[k];
        for (int ff = 0; ff < D_; ++ff) a += sH[s][i][ff] * Ws1[ff * N_ + k];
        sA[s][i][k] = fmaxf(a, 0.f);
    }
    __syncthreads();
    for (int idx = t; idx < 2 * N_ * N_; idx += 256) {
        int s = idx / (N_ * N_), rem = idx % (N_ * N_), i = rem / N_, k = rem % N_;
        float a = bs2[k];
        for (int j = 0; j < N_; ++j) a += sA[s][i][j] * Ws2[j * N_ + k];
        sT[s][i][k] = a;
    }
    __syncthreads();
    for (int idx = t; idx < N_ * N_; idx += 256) {
        int i = idx / N_, j = idx % N_;
        float c = 0.f;
        for (int k = 0; k < N_; ++k) c += fabsf(sT[0][i][k] - sT[1][j][k]);
        sLa[i][j] = -c * INV_TEMP;
    }
    if (t < N_) sV[t] = 0.f;
    __syncthreads();
    // sinkhorn in u/v potential form (matrix never rewritten)
    for (int it = 0; it < ITERS; ++it) {
        if (t < N_) {
            float m = -1e30f;
            for (int q = 0; q < N_; ++q) m = fmaxf(m, sLa[t][q] - sV[q]);
            float ss = 0.f;
            for (int q = 0; q < N_; ++q) ss += __expf(sLa[t][q] - sV[q] - m);
            sU[t] = m + __logf(ss);
        }
        __syncthreads();
        if (t < N_) {
            float m = -1e30f;
            for (int p = 0; p < N_; ++p) m = fmaxf(m, sLa[p][t] - sU[p]);
            float ss = 0.f;
            for (int p = 0; p < N_; ++p) ss += __expf(sLa[p][t] - sU[p] - m);
            sV[t] = m + __logf(ss);
        }
        __syncthreads();
    }
    for (int idx = t; idx < N_ * N_; idx += 256) {
        int i = idx / N_, j = idx % N_;
        Pg[b * N_ * N_ + idx] = __expf(sLa[i][j] - sU[i] - sV[j]);
    }
}

// ---------------------------------------------------------------- NC2 pair-edge embeddings (fwd+bwd fused)
#define PPW 4
__global__ __launch_bounds__(256) void k_edge(
    const float* __restrict__ h,
    const float* __restrict__ qadj, const float* __restrict__ cadj,
    const float* __restrict__ Wl1, const float* __restrict__ bl1,
    const float* __restrict__ Wl2, const float* __restrict__ bl2,
    float* __restrict__ emb)
{
    int wid = (blockIdx.x * 256 + threadIdx.x) >> 6;
    int f = threadIdx.x & 63;
    int base = wid * PPW;
    float sv[PPW], dv[PPW], av[PPW];
#pragma unroll
    for (int s = 0; s < PPW; ++s) {
        int slot = base + s;
        int g = slot / NC2, p = slot - g * NC2;
        int sp = PAIRS.s[p], dp = PAIRS.d[p];
        sv[s] = h[(g * N_ + sp) * D_ + f];
        dv[s] = h[(g * N_ + dp) * D_ + f];
        const float* adj = (g & 1) ? cadj : qadj;
        av[s] = adj[(g >> 1) * N_ * N_ + sp * N_ + dp];
    }
    float b1 = bl1[f];
    float w128 = Wl1[128 * D_ + f];
    float aF[PPW], aB[PPW];
#pragma unroll
    for (int s = 0; s < PPW; ++s) { float t0 = b1 + av[s] * w128; aF[s] = t0; aB[s] = t0; }
#pragma unroll 2
    for (int k = 0; k < D_; ++k) {
        float w0 = Wl1[k * D_ + f];
        float w1 = Wl1[(D_ + k) * D_ + f];
#pragma unroll
        for (int s = 0; s < PPW; ++s) {
            float a = rlane(sv[s], k), c = rlane(dv[s], k);
            aF[s] += a * w0 + c * w1;
            aB[s] += c * w0 + a * w1;
        }
    }
    float b2 = 2.f * bl2[f];
    float hs[PPW], out[PPW];
#pragma unroll
    for (int s = 0; s < PPW; ++s) {
        hs[s] = fmaxf(aF[s], 0.f) + fmaxf(aB[s], 0.f);
        out[s] = b2;
    }
#pragma unroll 4
    for (int k = 0; k < D_; ++k) {
        float w = Wl2[k * D_ + f];
#pragma unroll
        for (int s = 0; s < PPW; ++s) out[s] += rlane(hs[s], k) * w;
    }
#pragma unroll
    for (int s = 0; s < PPW; ++s) emb[(size_t)(base + s) * D_ + f] = out[s];
}

// ---------------------------------------------------------------- register-resident 190x190 sinkhorn
// thread (wave w, lane l) owns rows p=w+16i (i<12, wave-uniform valid count NR)
// and cols q=l+64r (r<3). Whole matrix in A[12][3] VGPRs; no global traffic in loop.
__global__ __launch_bounds__(1024) void k_sink(
    const float* __restrict__ Pg, float* __restrict__ eplan, float* __restrict__ dout)
{
    __shared__ float sP[N_][N_];
    __shared__ short sQs[NC2], sQd[NC2];
    __shared__ float rm[16][NC2], rs[16][NC2];
    __shared__ float sV[NC2];
    int b = blockIdx.x, t = threadIdx.x, w = t >> 6, l = t & 63;

    if (t < N_ * N_) sP[t / N_][t % N_] = Pg[b * N_ * N_ + t];
    if (t < NC2) { sQs[t] = (short)PAIRS.s[t]; sQd[t] = (short)PAIRS.d[t]; }
    if (t == 0) dout[b] = 0.f;
    __syncthreads();

    const int NR = (189 - w) / 16 + 1;   // 12 for w<=13, 11 for w=14,15 (wave-uniform)
    const int q0 = l, q1 = l + 64, q2 = l + 128;
    const bool v2 = (q2 < NC2);
    int sq0 = sQs[q0], dq0 = sQd[q0];
    int sq1 = sQs[q1], dq1 = sQd[q1];
    int sq2 = v2 ? sQs[q2] : 0, dq2 = v2 ? sQd[q2] : 0;

    float A[12][3], u[12];
    float vv0 = 0.f, vv1 = 0.f, vv2 = 0.f;

#pragma unroll
    for (int i = 0; i < 12; ++i) {
        if (i < NR) {
            int p = w + 16 * i;
            int sp = sQs[p], dp = sQd[p];
            const float* Ps = sP[sp];
            const float* Pd = sP[dp];
            float st0 = Ps[sq0] * Pd[dq0], cr0 = Ps[dq0] * Pd[sq0];
            A[i][0] = __logf(fmaxf(st0, cr0) + 1e-6f) * INV_TEMP;
            float st1 = Ps[sq1] * Pd[dq1], cr1 = Ps[dq1] * Pd[sq1];
            A[i][1] = __logf(fmaxf(st1, cr1) + 1e-6f) * INV_TEMP;
            if (v2) {
                float st2 = Ps[sq2] * Pd[dq2], cr2 = Ps[dq2] * Pd[sq2];
                A[i][2] = __logf(fmaxf(st2, cr2) + 1e-6f) * INV_TEMP;
            } else A[i][2] = -1e30f;
        } else { A[i][0] = A[i][1] = A[i][2] = -1e30f; u[i] = 0.f; }
    }

    for (int it = 0; it < ITERS; ++it) {
        // ---- row pass: u[p] = lse_q(A - v)  (pure register + butterfly)
#pragma unroll
        for (int i = 0; i < 12; ++i) {
            if (i < NR) {
                float x0 = A[i][0] - vv0, x1 = A[i][1] - vv1, x2 = A[i][2] - vv2;
                float m = fmaxf(fmaxf(x0, x1), x2);
#pragma unroll
                for (int off = 32; off; off >>= 1) m = fmaxf(m, __shfl_xor(m, off));
                float s = __expf(x0 - m) + __expf(x1 - m) + __expf(x2 - m);
#pragma unroll
                for (int off = 32; off; off >>= 1) s += __shfl_xor(s, off);
                u[i] = m + __logf(s);
            }
        }
        // ---- col partials over own rows
        float pm0 = -1e30f, pm1 = -1e30f, pm2 = -1e30f;
#pragma unroll
        for (int i = 0; i < 12; ++i) {
            if (i < NR) {
                pm0 = fmaxf(pm0, A[i][0] - u[i]);
                pm1 = fmaxf(pm1, A[i][1] - u[i]);
                pm2 = fmaxf(pm2, A[i][2] - u[i]);
            }
        }
        float ps0 = 0.f, ps1 = 0.f, ps2 = 0.f;
#pragma unroll
        for (int i = 0; i < 12; ++i) {
            if (i < NR) {
                ps0 += __expf(A[i][0] - u[i] - pm0);
                ps1 += __expf(A[i][1] - u[i] - pm1);
                ps2 += __expf(A[i][2] - u[i] - pm2);
            }
        }
        rm[w][q0] = pm0; rs[w][q0] = ps0;
        rm[w][q1] = pm1; rs[w][q1] = ps1;
        if (v2) { rm[w][q2] = pm2; rs[w][q2] = ps2; }
        __syncthreads();
        // ---- combine 16 wave-partials per column
        if (t < NC2) {
            float m = rm[0][t];
#pragma unroll
            for (int ww = 1; ww < 16; ++ww) m = fmaxf(m, rm[ww][t]);
            float s = 0.f;
#pragma unroll
            for (int ww = 0; ww < 16; ++ww) s += rs[ww][t] * __expf(rm[ww][t] - m);
            sV[t] = m + __logf(s);
        }
        __syncthreads();
        vv0 = sV[q0]; vv1 = sV[q1]; vv2 = v2 ? sV[q2] : 0.f;
    }

    // ---- eplan = exp(A - u - v), written coalesced
    float* ep = eplan + (size_t)b * NC2 * NC2;
#pragma unroll
    for (int i = 0; i < 12; ++i) {
        if (i < NR) {
            int p = w + 16 * i;
            float* row = ep + (size_t)p * NC2;
            row[q0] = __expf(A[i][0] - u[i] - vv0);
            row[q1] = __expf(A[i][1] - u[i] - vv1);
            if (v2) row[q2] = __expf(A[i][2] - u[i] - vv2);
        }
    }
}

// ---------------------------------------------------------------- final weighted L1 contraction
__global__ __launch_bounds__(256) void k_dist(
    const float* __restrict__ emb, const float* __restrict__ eplan, float* __restrict__ dout)
{
    int b = blockIdx.x, c = blockIdx.y;
    int w = threadIdx.x >> 6, l = threadIdx.x & 63;
    const float* qe = emb + (size_t)(2 * b) * NC2 * D_;
    const float* ce = emb + (size_t)(2 * b + 1) * NC2 * D_;
    const float* W = eplan + (size_t)b * NC2 * NC2;
    float acc = 0.f;
    int pbase = c * 16 + w * 4;
    for (int i = 0; i < 4; ++i) {
        int p = pbase + i;
        if (p >= NC2) break;
        float qv = qe[(size_t)p * D_ + l];
        const float* wrow = W + (size_t)p * NC2;
        for (int q = 0; q < NC2; ++q)
            acc += wrow[q] * fabsf(qv - ce[(size_t)q * D_ + l]);
    }
#pragma unroll
    for (int off = 32; off; off >>= 1) acc += __shfl_xor(acc, off);
    if (l == 0) atomicAdd(&dout[b], acc);
}

// ---------------------------------------------------------------- launch
extern "C" void kernel_launch(void* const* d_in, const int* in_sizes, int n_in,
                              void* d_out, int out_size, void* d_ws, size_t ws_size,
                              hipStream_t stream)
{
    const float* nf   = (const float*)d_in[0];
    const float* ef   = (const float*)d_in[1];
    const float* qadj = (const float*)d_in[2];
    const float* cadj = (const float*)d_in[3];
    const int*   fidx = (const int*)d_in[4];
    const int*   tidx = (const int*)d_in[5];
    const float* Wn  = (const float*)d_in[6];  const float* bn  = (const float*)d_in[7];
    const float* We  = (const float*)d_in[8];  const float* be  = (const float*)d_in[9];
    const float* Wm1 = (const float*)d_in[10]; const float* bm1 = (const float*)d_in[11];
    const float* Wm2 = (const float*)d_in[12]; const float* bm2 = (const float*)d_in[13];
    const float* Wu1 = (const float*)d_in[14]; const float* bu1 = (const float*)d_in[15];
    const float* Wu2 = (const float*)d_in[16]; const float* bu2 = (const float*)d_in[17];
    const float* Ws1 = (const float*)d_in[18]; const float* bs1 = (const float*)d_in[19];
    const float* Ws2 = (const float*)d_in[20]; const float* bs2 = (const float*)d_in[21];
    const float* Wl1 = (const float*)d_in[22]; const float* bl1 = (const float*)d_in[23];
    const float* Wl2 = (const float*)d_in[24]; const float* bl2 = (const float*)d_in[25];

    float* ws    = (float*)d_ws;
    float* h     = ws;                          // TN*D
    float* agg   = h    + (size_t)TN * D_;      // TN*D
    float* eemb  = agg  + (size_t)TN * D_;      // TE*D
    float* emb   = eemb + (size_t)TE * D_;      // NG*NC2*D
    float* eplan = emb  + (size_t)NG * NC2 * D_;   // B*NC2*NC2
    float* Pg    = eplan + (size_t)B_ * NC2 * NC2; // B*N*N
    float* dout  = (float*)d_out;

    k_encode<<<(TN + TE) * D_ / 256, 256, 0, stream>>>(nf, ef, Wn, bn, We, be, h, eemb, agg);
    for (int s = 0; s < PROP; ++s) {
        k_msg<<<TE / EPW / 4, 256, 0, stream>>>(h, eemb, fidx, tidx, Wm1, bm1, Wm2, bm2, agg);
        k_update<<<TN / NPW / 4, 256, 0, stream>>>(h, agg, Wu1, bu1, Wu2, bu2);
    }
    k_sim<<<B_, 256, 0, stream>>>(h, Ws1, bs1, Ws2, bs2, Pg);
    k_edge<<<NG * NC2 / PPW / 4, 256, 0, stream>>>(h, qadj, cadj, Wl1, bl1, Wl2, bl2, emb);
    k_sink<<<B_, 1024, 0, stream>>>(Pg, eplan, dout);
    k_dist<<<dim3(B_, 12), 256, 0, stream>>>(emb, eplan, dout);
}

// Round 3
// 315.033 us; speedup vs baseline: 2.0854x; 1.4790x over previous
//
#include <hip/hip_runtime.h>
#include <math.h>

#define B_     32
#define N_     20
#define D_     64
#define NODE_F 16
#define EDGE_F 8
#define E_PER  40
#define PROP   5
#define NC2    190
#define ITERS  20
#define INV_TEMP 10.0f
#define TN (2*B_*N_)    // 1280 nodes
#define TE (2*B_*E_PER) // 2560 edges
#define NG (2*B_)       // 64 graphs

struct PairTab { int s[NC2]; int d[NC2]; };
constexpr PairTab make_pairs() {
    PairTab t{};
    int idx = 0;
    for (int i = 0; i < N_; ++i)
        for (int j = i + 1; j < N_; ++j) { t.s[idx] = i; t.d[idx] = j; ++idx; }
    return t;
}
__device__ constexpr PairTab PAIRS = make_pairs();

// lane-broadcast: read element k of a lane-distributed vector (uniform k)
__device__ __forceinline__ float rlane(float x, int k) {
#if __has_builtin(__builtin_amdgcn_readlane)
    return __int_as_float(__builtin_amdgcn_readlane(__float_as_int(x), k));
#else
    return __shfl(x, k, 64);
#endif
}

// DPP rotation within each 16-lane row (VALU pipe, no LDS traffic)
template<int CTRL>
__device__ __forceinline__ float dppmov(float x) {
    return __int_as_float(__builtin_amdgcn_update_dpp(
        0, __float_as_int(x), CTRL, 0xf, 0xf, false));
}
// row_ror:1=0x121, :2=0x122, :4=0x124, :8=0x128
__device__ __forceinline__ float rowsum16(float x) {
    x += dppmov<0x121>(x);
    x += dppmov<0x122>(x);
    x += dppmov<0x124>(x);
    x += dppmov<0x128>(x);
    return x;
}
__device__ __forceinline__ float rowmax16(float x) {
    x = fmaxf(x, dppmov<0x121>(x));
    x = fmaxf(x, dppmov<0x122>(x));
    x = fmaxf(x, dppmov<0x124>(x));
    x = fmaxf(x, dppmov<0x128>(x));
    return x;
}
// reciprocal with one Newton step (~1 ulp)
__device__ __forceinline__ float nrcp(float x) {
    float r = __builtin_amdgcn_rcpf(x);
    r = r * fmaf(-x, r, 2.0f);
    return r;
}

// ---------------------------------------------------------------- encode
__global__ __launch_bounds__(256) void k_encode(
    const float* __restrict__ nf, const float* __restrict__ ef,
    const float* __restrict__ Wn, const float* __restrict__ bn,
    const float* __restrict__ We, const float* __restrict__ be,
    float* __restrict__ h, float* __restrict__ eemb, float* __restrict__ agg)
{
    int gid = blockIdx.x * 256 + threadIdx.x;
    int f = gid & 63, r = gid >> 6;
    if (r < TN) {
        float acc = bn[f];
#pragma unroll
        for (int k = 0; k < NODE_F; ++k) acc += nf[r * NODE_F + k] * Wn[k * D_ + f];
        h[r * D_ + f] = acc;
        agg[r * D_ + f] = 0.f;
    } else if (r < TN + TE) {
        int r2 = r - TN;
        float acc = be[f];
#pragma unroll
        for (int k = 0; k < EDGE_F; ++k) acc += ef[r2 * EDGE_F + k] * We[k * D_ + f];
        eemb[r2 * D_ + f] = acc;
    }
}

// ---------------------------------------------------------------- message + aggregate
#define EPW 4
__global__ __launch_bounds__(256) void k_msg(
    const float* __restrict__ h, const float* __restrict__ eemb,
    const int* __restrict__ fidx, const int* __restrict__ tidx,
    const float* __restrict__ Wm1, const float* __restrict__ bm1,
    const float* __restrict__ Wm2, const float* __restrict__ bm2,
    float* __restrict__ agg)
{
    int wid = (blockIdx.x * 256 + threadIdx.x) >> 6;
    int f = threadIdx.x & 63;
    int ebase = wid * EPW;
    float xf[EPW], xt[EPW], xe[EPW];
    int to[EPW];
#pragma unroll
    for (int s = 0; s < EPW; ++s) {
        int e = ebase + s;
        int fr = fidx[e]; to[s] = tidx[e];
        xf[s] = h[fr * D_ + f];
        xt[s] = h[to[s] * D_ + f];
        xe[s] = eemb[e * D_ + f];
    }
    float b1 = bm1[f];
    float acc[EPW];
#pragma unroll
    for (int s = 0; s < EPW; ++s) acc[s] = b1;
#pragma unroll 4
    for (int k = 0; k < D_; ++k) {
        float w0 = Wm1[k * D_ + f];
        float w1 = Wm1[(D_ + k) * D_ + f];
        float w2 = Wm1[(2 * D_ + k) * D_ + f];
#pragma unroll
        for (int s = 0; s < EPW; ++s)
            acc[s] += rlane(xf[s], k) * w0 + rlane(xt[s], k) * w1 + rlane(xe[s], k) * w2;
    }
    float b2 = bm2[f];
    float out[EPW];
#pragma unroll
    for (int s = 0; s < EPW; ++s) { acc[s] = fmaxf(acc[s], 0.f); out[s] = b2; }
#pragma unroll 4
    for (int k = 0; k < D_; ++k) {
        float w = Wm2[k * D_ + f];
#pragma unroll
        for (int s = 0; s < EPW; ++s) out[s] += rlane(acc[s], k) * w;
    }
#pragma unroll
    for (int s = 0; s < EPW; ++s) atomicAdd(&agg[to[s] * D_ + f], out[s]);
}

// ---------------------------------------------------------------- node update (in-place, re-zeroes agg)
#define NPW 2
__global__ __launch_bounds__(256) void k_update(
    float* __restrict__ h, float* __restrict__ agg,
    const float* __restrict__ Wu1, const float* __restrict__ bu1,
    const float* __restrict__ Wu2, const float* __restrict__ bu2)
{
    int wid = (blockIdx.x * 256 + threadIdx.x) >> 6;
    int f = threadIdx.x & 63;
    int nbase = wid * NPW;
    float xh[NPW], xa[NPW];
#pragma unroll
    for (int s = 0; s < NPW; ++s) {
        xh[s] = h[(nbase + s) * D_ + f];
        xa[s] = agg[(nbase + s) * D_ + f];
    }
    float b1 = bu1[f];
    float acc[NPW];
#pragma unroll
    for (int s = 0; s < NPW; ++s) acc[s] = b1;
#pragma unroll 4
    for (int k = 0; k < D_; ++k) {
        float w0 = Wu1[k * D_ + f];
        float w1 = Wu1[(D_ + k) * D_ + f];
#pragma unroll
        for (int s = 0; s < NPW; ++s)
            acc[s] += rlane(xh[s], k) * w0 + rlane(xa[s], k) * w1;
    }
    float b2 = bu2[f];
    float out[NPW];
#pragma unroll
    for (int s = 0; s < NPW; ++s) { acc[s] = fmaxf(acc[s], 0.f); out[s] = b2; }
#pragma unroll 4
    for (int k = 0; k < D_; ++k) {
        float w = Wu2[k * D_ + f];
#pragma unroll
        for (int s = 0; s < NPW; ++s) out[s] += rlane(acc[s], k) * w;
    }
#pragma unroll
    for (int s = 0; s < NPW; ++s) {
        h[(nbase + s) * D_ + f] = out[s];
        agg[(nbase + s) * D_ + f] = 0.f;   // ready for next prop step
    }
}

// ---------------------------------------------------------------- NC2 pair-edge embeddings (fwd+bwd fused)
#define PPW 4
__global__ __launch_bounds__(256) void k_edge(
    const float* __restrict__ h,
    const float* __restrict__ qadj, const float* __restrict__ cadj,
    const float* __restrict__ Wl1, const float* __restrict__ bl1,
    const float* __restrict__ Wl2, const float* __restrict__ bl2,
    float* __restrict__ emb)
{
    int wid = (blockIdx.x * 256 + threadIdx.x) >> 6;
    int f = threadIdx.x & 63;
    int base = wid * PPW;
    float sv[PPW], dv[PPW], av[PPW];
#pragma unroll
    for (int s = 0; s < PPW; ++s) {
        int slot = base + s;
        int g = slot / NC2, p = slot - g * NC2;
        int sp = PAIRS.s[p], dp = PAIRS.d[p];
        sv[s] = h[(g * N_ + sp) * D_ + f];
        dv[s] = h[(g * N_ + dp) * D_ + f];
        const float* adj = (g & 1) ? cadj : qadj;
        av[s] = adj[(g >> 1) * N_ * N_ + sp * N_ + dp];
    }
    float b1 = bl1[f];
    float w128 = Wl1[128 * D_ + f];
    float aF[PPW], aB[PPW];
#pragma unroll
    for (int s = 0; s < PPW; ++s) { float t0 = b1 + av[s] * w128; aF[s] = t0; aB[s] = t0; }
#pragma unroll 2
    for (int k = 0; k < D_; ++k) {
        float w0 = Wl1[k * D_ + f];
        float w1 = Wl1[(D_ + k) * D_ + f];
#pragma unroll
        for (int s = 0; s < PPW; ++s) {
            float a = rlane(sv[s], k), c = rlane(dv[s], k);
            aF[s] += a * w0 + c * w1;
            aB[s] += c * w0 + a * w1;
        }
    }
    float b2 = 2.f * bl2[f];
    float hs[PPW], out[PPW];
#pragma unroll
    for (int s = 0; s < PPW; ++s) {
        hs[s] = fmaxf(aF[s], 0.f) + fmaxf(aB[s], 0.f);
        out[s] = b2;
    }
#pragma unroll 4
    for (int k = 0; k < D_; ++k) {
        float w = Wl2[k * D_ + f];
#pragma unroll
        for (int s = 0; s < PPW; ++s) out[s] += rlane(hs[s], k) * w;
    }
#pragma unroll
    for (int s = 0; s < PPW; ++s) emb[(size_t)(base + s) * D_ + f] = out[s];
}

// ---------------------------------------------------------------- fused sim + multiplicative 190x190 sinkhorn
// Layout: wave w (16), lane l: group g=l>>4, l16=l&15. row-slot = w*4+g (64 slots).
// Thread owns rows p = rslot+64*i (i<3, p<190) and cols q = l16+16*j (j<12, q<190).
// E = exp(la) maintained multiplicatively: row/col normalize are sums + reciprocals,
// row reduce = DPP 16-lane rotation sum (VALU only), col reduce via LDS colbuf.
__global__ __launch_bounds__(1024) void k_simsink(
    const float* __restrict__ h,
    const float* __restrict__ Ws1, const float* __restrict__ bs1,
    const float* __restrict__ Ws2, const float* __restrict__ bs2,
    float* __restrict__ eplan, float* __restrict__ dout)
{
    __shared__ float sH[2][N_][D_];
    __shared__ float sA[2][N_][N_];
    __shared__ float sT[2][N_][N_];
    __shared__ float sLa[N_][N_];
    __shared__ float sU20[N_], sV20[N_];
    __shared__ float sP[N_][N_];
    __shared__ float colbuf[64][200];   // pitch 200: 2-way bank aliasing only (free)
    __shared__ float sInvC[192];
    __shared__ short sQs[192], sQd[192];
    int b = blockIdx.x, t = threadIdx.x;

    // ================= sim phase (T-MLP + 20x20 log-domain sinkhorn) =================
    for (int idx = t; idx < 2 * N_ * D_; idx += 1024) {
        int s = idx / (N_ * D_), rem = idx % (N_ * D_), i = rem / D_, f = rem % D_;
        sH[s][i][f] = h[((2 * b + s) * N_ + i) * D_ + f];
    }
    __syncthreads();
    for (int idx = t; idx < 2 * N_ * N_; idx += 1024) {
        int s = idx / (N_ * N_), rem = idx % (N_ * N_), i = rem / N_, k = rem % N_;
        float a = bs1[k];
        for (int ff = 0; ff < D_; ++ff) a += sH[s][i][ff] * Ws1[ff * N_ + k];
        sA[s][i][k] = fmaxf(a, 0.f);
    }
    __syncthreads();
    for (int idx = t; idx < 2 * N_ * N_; idx += 1024) {
        int s = idx / (N_ * N_), rem = idx % (N_ * N_), i = rem / N_, k = rem % N_;
        float a = bs2[k];
        for (int j = 0; j < N_; ++j) a += sA[s][i][j] * Ws2[j * N_ + k];
        sT[s][i][k] = a;
    }
    __syncthreads();
    for (int idx = t; idx < N_ * N_; idx += 1024) {
        int i = idx / N_, j = idx % N_;
        float c = 0.f;
        for (int k = 0; k < N_; ++k) c += fabsf(sT[0][i][k] - sT[1][j][k]);
        sLa[i][j] = -c * INV_TEMP;
    }
    if (t < N_) sV20[t] = 0.f;
    __syncthreads();
    for (int it = 0; it < ITERS; ++it) {
        if (t < N_) {
            float m = -1e30f;
            for (int q = 0; q < N_; ++q) m = fmaxf(m, sLa[t][q] - sV20[q]);
            float ss = 0.f;
            for (int q = 0; q < N_; ++q) ss += __expf(sLa[t][q] - sV20[q] - m);
            sU20[t] = m + __logf(ss);
        }
        __syncthreads();
        if (t < N_) {
            float m = -1e30f;
            for (int p = 0; p < N_; ++p) m = fmaxf(m, sLa[p][t] - sU20[p]);
            float ss = 0.f;
            for (int p = 0; p < N_; ++p) ss += __expf(sLa[p][t] - sU20[p] - m);
            sV20[t] = m + __logf(ss);
        }
        __syncthreads();
    }
    if (t < N_ * N_) {
        int i = t / N_, j = t % N_;
        sP[i][j] = __expf(sLa[i][j] - sU20[i] - sV20[j]);
    }
    if (t < 192) {
        int tt = t < NC2 ? t : NC2 - 1;
        sQs[t] = (short)PAIRS.s[tt];
        sQd[t] = (short)PAIRS.d[tt];
    }
    if (t == 0) dout[b] = 0.f;
    __syncthreads();

    // ================= sink phase (multiplicative) =================
    int w = t >> 6, l = t & 63, g = l >> 4, l16 = l & 15;
    int rslot = w * 4 + g;

    int sp[3], dp[3];
    bool pv[3];
#pragma unroll
    for (int i = 0; i < 3; ++i) {
        int p = rslot + 64 * i;
        pv[i] = (p < NC2);
        int pp = pv[i] ? p : 0;
        sp[i] = sQs[pp]; dp[i] = sQd[pp];
    }
    int sq[12], dq[12];
    bool qv[12];
#pragma unroll
    for (int j = 0; j < 12; ++j) {
        int q = l16 + 16 * j;
        qv[j] = (q < NC2);
        int qq = qv[j] ? q : 0;
        sq[j] = sQs[qq]; dq[j] = sQd[qq];
    }

    // init: E = ((esi+1e-6)/rowmax)^10
    float E[3][12];
#pragma unroll
    for (int i = 0; i < 3; ++i) {
        float mi = 1e-30f;
#pragma unroll
        for (int j = 0; j < 12; ++j) {
            float x = 0.f;
            if (pv[i] && qv[j]) {
                float st = sP[sp[i]][sq[j]] * sP[dp[i]][dq[j]];
                float cr = sP[sp[i]][dq[j]] * sP[dp[i]][sq[j]];
                x = fmaxf(st, cr) + 1e-6f;
            }
            E[i][j] = x;
            mi = fmaxf(mi, x);
        }
        mi = rowmax16(mi);
        float invm = nrcp(mi);
#pragma unroll
        for (int j = 0; j < 12; ++j) {
            float r = E[i][j] * invm;
            float r2 = r * r, r4 = r2 * r2, r8 = r4 * r4;
            E[i][j] = r8 * r2;                 // r^10
        }
    }

    float invS[3];
    for (int it = 0; it < ITERS; ++it) {
        // row sums (DPP rotation reduce, no LDS)
#pragma unroll
        for (int i = 0; i < 3; ++i) {
            float s01 = E[i][0] + E[i][1], s23 = E[i][2] + E[i][3];
            float s45 = E[i][4] + E[i][5], s67 = E[i][6] + E[i][7];
            float s89 = E[i][8] + E[i][9], sab = E[i][10] + E[i][11];
            float S = ((s01 + s23) + (s45 + s67)) + (s89 + sab);
            S = rowsum16(S);
            invS[i] = nrcp(fmaxf(S, 1e-30f));
        }
        // col partials (row-normalized values, folded)
#pragma unroll
        for (int j = 0; j < 12; ++j) {
            float pc = E[0][j] * invS[0];
            pc = fmaf(E[1][j], invS[1], pc);
            pc = fmaf(E[2][j], invS[2], pc);
            colbuf[rslot][l16 + 16 * j] = pc;
        }
        __syncthreads();
        // combine 64 slot-partials per column
        if (t < 192) {
            float a0 = 0.f, a1 = 0.f, a2 = 0.f, a3 = 0.f;
#pragma unroll
            for (int s = 0; s < 16; ++s) {
                a0 += colbuf[4 * s + 0][t];
                a1 += colbuf[4 * s + 1][t];
                a2 += colbuf[4 * s + 2][t];
                a3 += colbuf[4 * s + 3][t];
            }
            float c = (a0 + a1) + (a2 + a3);
            sInvC[t] = nrcp(fmaxf(c, 1e-30f));
        }
        __syncthreads();
        float ic[12];
#pragma unroll
        for (int j = 0; j < 12; ++j) ic[j] = sInvC[l16 + 16 * j];
#pragma unroll
        for (int i = 0; i < 3; ++i) {
#pragma unroll
            for (int j = 0; j < 12; ++j) {
                float tmp = E[i][j] * invS[i];   // mul order matters: keeps 0*big = 0
                E[i][j] = tmp * ic[j];
            }
        }
    }

    // E is now eplan; write out
    float* ep = eplan + (size_t)b * NC2 * NC2;
#pragma unroll
    for (int i = 0; i < 3; ++i) {
        if (pv[i]) {
            int p = rslot + 64 * i;
            float* row = ep + (size_t)p * NC2;
#pragma unroll
            for (int j = 0; j < 12; ++j) {
                if (qv[j]) row[l16 + 16 * j] = E[i][j];
            }
        }
    }
}

// ---------------------------------------------------------------- final weighted L1 contraction
__global__ __launch_bounds__(256) void k_dist(
    const float* __restrict__ emb, const float* __restrict__ eplan, float* __restrict__ dout)
{
    int b = blockIdx.x, c = blockIdx.y;
    int w = threadIdx.x >> 6, l = threadIdx.x & 63;
    const float* qe = emb + (size_t)(2 * b) * NC2 * D_;
    const float* ce = emb + (size_t)(2 * b + 1) * NC2 * D_;
    const float* W = eplan + (size_t)b * NC2 * NC2;
    float acc = 0.f;
    int pbase = c * 16 + w * 4;
    for (int i = 0; i < 4; ++i) {
        int p = pbase + i;
        if (p >= NC2) break;
        float qv = qe[(size_t)p * D_ + l];
        const float* wrow = W + (size_t)p * NC2;
        for (int q = 0; q < NC2; ++q)
            acc += wrow[q] * fabsf(qv - ce[(size_t)q * D_ + l]);
    }
#pragma unroll
    for (int off = 32; off; off >>= 1) acc += __shfl_xor(acc, off);
    if (l == 0) atomicAdd(&dout[b], acc);
}

// ---------------------------------------------------------------- launch
extern "C" void kernel_launch(void* const* d_in, const int* in_sizes, int n_in,
                              void* d_out, int out_size, void* d_ws, size_t ws_size,
                              hipStream_t stream)
{
    const float* nf   = (const float*)d_in[0];
    const float* ef   = (const float*)d_in[1];
    const float* qadj = (const float*)d_in[2];
    const float* cadj = (const float*)d_in[3];
    const int*   fidx = (const int*)d_in[4];
    const int*   tidx = (const int*)d_in[5];
    const float* Wn  = (const float*)d_in[6];  const float* bn  = (const float*)d_in[7];
    const float* We  = (const float*)d_in[8];  const float* be  = (const float*)d_in[9];
    const float* Wm1 = (const float*)d_in[10]; const float* bm1 = (const float*)d_in[11];
    const float* Wm2 = (const float*)d_in[12]; const float* bm2 = (const float*)d_in[13];
    const float* Wu1 = (const float*)d_in[14]; const float* bu1 = (const float*)d_in[15];
    const float* Wu2 = (const float*)d_in[16]; const float* bu2 = (const float*)d_in[17];
    const float* Ws1 = (const float*)d_in[18]; const float* bs1 = (const float*)d_in[19];
    const float* Ws2 = (const float*)d_in[20]; const float* bs2 = (const float*)d_in[21];
    const float* Wl1 = (const float*)d_in[22]; const float* bl1 = (const float*)d_in[23];
    const float* Wl2 = (const float*)d_in[24]; const float* bl2 = (const float*)d_in[25];

    float* ws    = (float*)d_ws;
    float* h     = ws;                          // TN*D
    float* agg   = h    + (size_t)TN * D_;      // TN*D
    float* eemb  = agg  + (size_t)TN * D_;      // TE*D
    float* emb   = eemb + (size_t)TE * D_;      // NG*NC2*D
    float* eplan = emb  + (size_t)NG * NC2 * D_;   // B*NC2*NC2
    float* dout  = (float*)d_out;

    k_encode<<<(TN + TE) * D_ / 256, 256, 0, stream>>>(nf, ef, Wn, bn, We, be, h, eemb, agg);
    for (int s = 0; s < PROP; ++s) {
        k_msg<<<TE / EPW / 4, 256, 0, stream>>>(h, eemb, fidx, tidx, Wm1, bm1, Wm2, bm2, agg);
        k_update<<<TN / NPW / 4, 256, 0, stream>>>(h, agg, Wu1, bu1, Wu2, bu2);
    }
    k_simsink<<<B_, 1024, 0, stream>>>(h, Ws1, bs1, Ws2, bs2, eplan, dout);
    k_edge<<<NG * NC2 / PPW / 4, 256, 0, stream>>>(h, qadj, cadj, Wl1, bl1, Wl2, bl2, emb);
    k_dist<<<dim3(B_, 12), 256, 0, stream>>>(emb, eplan, dout);
}